// Round 19
// baseline (196.330 us; speedup 1.0000x reference)
//
#include <hip/hip_runtime.h>
#include <hip/hip_bf16.h>
#include <cstdint>
#include <math.h>

#define D_DIM 1024
#define TAU_INV 10.0f
// K stored as e4m3(64 * k_hat): acc = 4096 * sim -> exp(acc * TAU_INV/4096)
#define EXP_SCALE (TAU_INV / 4096.0f)
#define BK 64                  // 64 fp8 = 64 B per row chunk
#define NT (D_DIM / BK)        // 16 K-tiles
#define BM 256                 // tile rows
#define BN 128                 // tile cols
#define SLOT 24576             // ring slot: A 16K + B 8K

typedef float f32x4 __attribute__((ext_vector_type(4)));
typedef long  l64x2 __attribute__((ext_vector_type(2)));

#define VMCNT(n) asm volatile("s_waitcnt vmcnt(" #n ")" ::: "memory")
#define LGKM0()  asm volatile("s_waitcnt lgkmcnt(0)" ::: "memory")
#define BAR() do { asm volatile("" ::: "memory"); \
                   __builtin_amdgcn_s_barrier();  \
                   asm volatile("" ::: "memory"); } while (0)

__device__ __forceinline__ float wave_reduce_add(float v) {
#pragma unroll
    for (int off = 32; off > 0; off >>= 1) v += __shfl_xor(v, off, 64);
    return v;
}

// ---- Kernel A (fused): normalize -> fp8 K (x64 pre-scale, INTERLEAVED),
//      positives, zero rowsum, zero out.
// Interleaved row layout (R14-verified): within each 64B K-tile chunk, 8B
// chunks ordered [g0h0][g0h1]...[g3h1] so a GEMM lane's full K=64 fragment is
// one contiguous 16B slot. Thread t (logical k = 4t..4t+3) -> physical word
// w = (t>>4)*16 + ((t>>1)&3)*4 + ((t>>3)&1)*2 + (t&1).
__global__ __launch_bounds__(256)
void norm_pos_kernel(const float* __restrict__ zi, const float* __restrict__ zj,
                     unsigned int* __restrict__ Kf, float* __restrict__ rowsum,
                     float* __restrict__ pos, float* __restrict__ out, int n_half) {
    const int i = blockIdx.x;
    const int t = threadIdx.x;                 // 256 threads x 4 floats = 1024
    float4 a = reinterpret_cast<const float4*>(zi + (size_t)i * D_DIM)[t];
    float4 b = reinterpret_cast<const float4*>(zj + (size_t)i * D_DIM)[t];
    float ssa = a.x*a.x + a.y*a.y + a.z*a.z + a.w*a.w;
    float ssb = b.x*b.x + b.y*b.y + b.z*b.z + b.w*b.w;
    float dab = a.x*b.x + a.y*b.y + a.z*b.z + a.w*b.w;
    ssa = wave_reduce_add(ssa);
    ssb = wave_reduce_add(ssb);
    dab = wave_reduce_add(dab);
    __shared__ float wsa[4], wsb[4], wsd[4];
    if ((t & 63) == 0) { wsa[t>>6] = ssa; wsb[t>>6] = ssb; wsd[t>>6] = dab; }
    __syncthreads();
    const float inva = 1.0f / sqrtf(wsa[0] + wsa[1] + wsa[2] + wsa[3]);
    const float invb = 1.0f / sqrtf(wsb[0] + wsb[1] + wsb[2] + wsb[3]);
    const float sa = inva * 64.0f;             // x64: keeps e4m3 in normal range
    const float sb = invb * 64.0f;
    unsigned int ua = 0, ub = 0;
    ua = __builtin_amdgcn_cvt_pk_fp8_f32(a.x * sa, a.y * sa, ua, false);
    ua = __builtin_amdgcn_cvt_pk_fp8_f32(a.z * sa, a.w * sa, ua, true);
    ub = __builtin_amdgcn_cvt_pk_fp8_f32(b.x * sb, b.y * sb, ub, false);
    ub = __builtin_amdgcn_cvt_pk_fp8_f32(b.z * sb, b.w * sb, ub, true);
    const int w = (t >> 4) * 16 + ((t >> 1) & 3) * 4 + ((t >> 3) & 1) * 2 + (t & 1);
    Kf[(size_t)i * 256 + w] = ua;                          // 1024 B row = 256 u32
    Kf[(size_t)(i + n_half) * 256 + w] = ub;
    if (t == 0) {
        pos[i] = (wsd[0] + wsd[1] + wsd[2] + wsd[3]) * inva * invb;
        rowsum[i] = 0.0f;
        rowsum[i + n_half] = 0.0f;
        if (i == 0) out[0] = 0.0f;             // loss kernel atomically accumulates
    }
}

// ---- Kernel B: triangular 256x128 tiles of S, fp8 plain MFMA ----------------
// R14 config (empirical optimum: R15/R16/R17 geometry variants all regressed)
// + T14 read-ahead: reads(t+1) issued right after BAR(t) into a ping-pong
// register set, so mma-hi(t) covers the LDS read latency and mma-lo(t+1)
// starts data-ready (R14 paid ~120+cyc lgkm stall per K-tile block-wide).
// Per K-tile t (slot t%3, fully unrolled so slots are compile-time):
//   stage_all(t+2)                          [3 gloads]
//   mma-lo(t)  [cur regs, .x halves; data pre-read last iter]
//   LGKM0 ; VMCNT(3) ; BAR                  [publish tile t+1]
//   readAB(t+1 -> other reg set)            [8 ds_read_b128, 0-conflict]
//   mma-hi(t)  [cur regs, .y halves; covers the reads' latency]
// Safety: reads(t) drained by LGKM0(t) before BAR(t) (< any wave's
// stage(t+3) issue at iter t+1) -> slot-reuse ordered, as since R4.
// Residency: VMCNT(3)@t leaves only stage(t+2) outstanding -> stage(t+1)
// complete -> BAR publishes t+1 for the immediately following reads.
// Tail: t==NT-2 VMCNT(0); t==NT-1 no wait/BAR/reads.
// diag (bx>>1==by): row-reduction only, exact diagonal zeroed; else row+col.
__global__ __launch_bounds__(512, 4)
void simclr_gemm_kernel(const unsigned char* __restrict__ Kmat,
                        float* __restrict__ rowsum, int n_total) {
    __shared__ char lds[73728];

    const int tid  = threadIdx.x;
    const int lane = tid & 63;
    const int wave = tid >> 6;          // 0..7
    const int wr = wave >> 1;           // 0..3  (A rows wr*64)
    const int wc = wave & 1;            // 0..1  (B cols wc*64)
    const int kgrp = lane >> 4;         // 16B fragment slot within 64B row

    // bijective XCD swizzle: nwg = 1056 = 8 * 132
    const int wg = (blockIdx.x & 7) * 132 + (blockIdx.x >> 3);

    // decode wg -> (by, bx): by in [0,32), bx in [2*by, 64)
    int by = 0, start = 0;
    while (wg >= start + (64 - 2 * by)) { start += 64 - 2 * by; ++by; }
    const int bx = 2 * by + (wg - start);
    const bool diag = ((bx >> 1) == by);
    const int rowbase = by * BM;
    const int colbase = bx * BN;

    const char* gK = reinterpret_cast<const char*>(Kmat);
    const int srow = tid >> 2;                          // 0..127 per 8KB issue
    const int sswz = (tid & 3) ^ ((srow >> 1) & 3);     // inverse-swizzled slot

    // stage full K-tile tt into ring slot tt%3: A 2 issues + B 1 issue
    auto stage_all = [&](int tt) {
        const int s = tt % 3;
        const size_t kbyte = (size_t)tt * BK;           // 64 B per row chunk
        char* dstA = lds + s * SLOT + tid * 16;
        char* dstB = lds + s * SLOT + 16384 + tid * 16;
#pragma unroll
        for (int i = 0; i < 2; ++i) {
            const int row = i * 128 + srow;
            const char* src = gK + (size_t)(rowbase + row) * D_DIM + kbyte + sswz * 16;
            __builtin_amdgcn_global_load_lds(
                (const __attribute__((address_space(1))) void*)src,
                (__attribute__((address_space(3))) void*)(dstA + i * 8192),
                16, 0, 0);
        }
        {
            const char* src = gK + (size_t)(colbase + srow) * D_DIM + kbyte + sswz * 16;
            __builtin_amdgcn_global_load_lds(
                (const __attribute__((address_space(1))) void*)src,
                (__attribute__((address_space(3))) void*)dstB,
                16, 0, 0);
        }
    };

    f32x4 acc[4][4] = {};                  // [mi][ni] 16x16 frags (AGPR path)
    l64x2 afA[4], bfA[4], afB[4], bfB[4];  // ping-pong fragment sets

    auto read_frag = [&](const char* base, int row) -> l64x2 {
        return *reinterpret_cast<const l64x2*>(
            base + row * 64 + ((kgrp ^ ((row >> 1) & 3)) << 4));
    };
    auto readAB = [&](int s, l64x2* af, l64x2* bf) {
        const char* Ab = lds + s * SLOT;
        const char* Bb = Ab + 16384;
#pragma unroll
        for (int mi = 0; mi < 4; ++mi)
            af[mi] = read_frag(Ab, wr * 64 + mi * 16 + (lane & 15));
#pragma unroll
        for (int ni = 0; ni < 4; ++ni)
            bf[ni] = read_frag(Bb, wc * 64 + ni * 16 + (lane & 15));
    };
    auto mma_lo = [&](const l64x2* af, const l64x2* bf) {
        __builtin_amdgcn_s_setprio(1);
#pragma unroll
        for (int mi = 0; mi < 4; ++mi)
#pragma unroll
            for (int ni = 0; ni < 4; ++ni)
                acc[mi][ni] = __builtin_amdgcn_mfma_f32_16x16x32_fp8_fp8(
                    af[mi].x, bf[ni].x, acc[mi][ni], 0, 0, 0);
        __builtin_amdgcn_s_setprio(0);
    };
    auto mma_hi = [&](const l64x2* af, const l64x2* bf) {
        __builtin_amdgcn_s_setprio(1);
#pragma unroll
        for (int mi = 0; mi < 4; ++mi)
#pragma unroll
            for (int ni = 0; ni < 4; ++ni)
                acc[mi][ni] = __builtin_amdgcn_mfma_f32_16x16x32_fp8_fp8(
                    af[mi].y, bf[ni].y, acc[mi][ni], 0, 0, 0);
        __builtin_amdgcn_s_setprio(0);
    };

    // prologue: tiles 0,1 staged; publish tile 0; pre-read tile 0 fragments
    stage_all(0); stage_all(1);
    VMCNT(3); BAR();
    readAB(0, afA, bfA);

#pragma unroll
    for (int tt = 0; tt < NT / 2; ++tt) {
        const int t = 2 * tt;
        // ---- even iter t: cur = A set, next = B set
        if (t + 2 < NT) stage_all(t + 2);
        mma_lo(afA, bfA);
        LGKM0();
        if (t < NT - 2) { VMCNT(3); } else { VMCNT(0); }
        BAR();                                          // publish tile t+1
        readAB((t + 1) % 3, afB, bfB);                  // latency hides under mma_hi
        mma_hi(afA, bfA);
        // ---- odd iter t+1: cur = B set, next = A set
        if (t + 3 < NT) stage_all(t + 3);
        mma_lo(afB, bfB);
        if (t + 1 < NT - 1) {
            LGKM0();
            if (t + 1 < NT - 2) { VMCNT(3); } else { VMCNT(0); }
            BAR();                                      // publish tile t+2
            readAB((t + 2) % 3, afA, bfA);
        }
        mma_hi(afB, bfB);
    }

    // Epilogue. C-frag: col = lane&15, row = (lane>>4)*4 + reg.
    float colpart[4] = {0.0f, 0.0f, 0.0f, 0.0f};
#pragma unroll
    for (int mi = 0; mi < 4; ++mi) {
#pragma unroll
        for (int reg = 0; reg < 4; ++reg) {
            const int grow = rowbase + wr * 64 + mi * 16 + ((lane >> 4) << 2) + reg;
            float rowpart = 0.0f;
#pragma unroll
            for (int ni = 0; ni < 4; ++ni) {
                const int gcol = colbase + wc * 64 + ni * 16 + (lane & 15);
                float e = __expf(acc[mi][ni][reg] * EXP_SCALE);
                if (diag && grow == gcol) e = 0.0f;
                rowpart += e;
                colpart[ni] += e;
            }
#pragma unroll
            for (int off = 1; off < 16; off <<= 1)
                rowpart += __shfl_xor(rowpart, off, 64);
            if ((lane & 15) == 0) atomicAdd(&rowsum[grow], rowpart);
        }
    }
    if (!diag) {
#pragma unroll
        for (int ni = 0; ni < 4; ++ni) {
            float cp = colpart[ni];
            cp += __shfl_xor(cp, 16, 64);
            cp += __shfl_xor(cp, 32, 64);
            if (lane < 16)
                atomicAdd(&rowsum[colbase + wc * 64 + ni * 16 + lane], cp);
        }
    }
}

// ---- Kernel C: loss = mean(log(denom) - pos/tau), 32 blocks + atomicAdd ----
__global__ __launch_bounds__(256)
void loss_kernel(const float* __restrict__ rowsum, const float* __restrict__ pos,
                 float* __restrict__ out, int n_total, int n_half) {
    const int t = threadIdx.x;
    const int r = blockIdx.x * 256 + t;                 // 32 x 256 = 8192
    const int pi = (r < n_half) ? r : (r - n_half);
    float v = logf(rowsum[r]) - TAU_INV * pos[pi];
    v = wave_reduce_add(v);
    __shared__ float ws4[4];
    if ((t & 63) == 0) ws4[t >> 6] = v;
    __syncthreads();
    if (t == 0)
        atomicAdd(out, (ws4[0] + ws4[1] + ws4[2] + ws4[3]) / (float)n_total);
}

extern "C" void kernel_launch(void* const* d_in, const int* in_sizes, int n_in,
                              void* d_out, int out_size, void* d_ws, size_t ws_size,
                              hipStream_t stream) {
    const float* zi = (const float*)d_in[0];
    const float* zj = (const float*)d_in[1];
    float* out = (float*)d_out;

    const int n_half  = in_sizes[0] / D_DIM;   // 4096
    const int n_total = 2 * n_half;            // 8192

    char* ws = (char*)d_ws;
    unsigned int* Kf = (unsigned int*)ws;                 // 8192 x 1024 fp8 = 8 MB
    size_t off = (size_t)n_total * D_DIM;
    float* rowsum = (float*)(ws + off); off += (size_t)n_total * 4;
    float* pos    = (float*)(ws + off); off += (size_t)n_half * 4;

    norm_pos_kernel<<<n_half, 256, 0, stream>>>(zi, zj, Kf, rowsum, pos, out, n_half);

    // triangular 256x128 tiles: sum_{by=0}^{31} (64 - 2*by) = 1056 blocks
    simclr_gemm_kernel<<<1056, 512, 0, stream>>>((const unsigned char*)Kf,
                                                 rowsum, n_total);

    loss_kernel<<<n_total / 256, 256, 0, stream>>>(rowsum, pos, out, n_total, n_half);
}

// Round 20
// 99.487 us; speedup vs baseline: 1.9734x; 1.9734x over previous
//
#include <hip/hip_runtime.h>
#include <hip/hip_bf16.h>
#include <cstdint>
#include <math.h>

#define D_DIM 1024
#define TAU_INV 10.0f
// K stored as e4m3(64 * k_hat): acc = 4096 * sim -> exp(acc * TAU_INV/4096)
#define EXP_SCALE (TAU_INV / 4096.0f)
#define BK 64                  // 64 fp8 = 64 B per row chunk
#define NT (D_DIM / BK)        // 16 K-tiles
#define BM 256                 // tile rows
#define BN 128                 // tile cols
#define SLOT 24576             // ring slot: A 16K + B 8K
#define NSPLIT 32              // tiles (by=0, bx<32) quartered along K

typedef float f32x4 __attribute__((ext_vector_type(4)));
typedef long  l64x2 __attribute__((ext_vector_type(2)));

#define VMCNT(n) asm volatile("s_waitcnt vmcnt(" #n ")" ::: "memory")
#define LGKM0()  asm volatile("s_waitcnt lgkmcnt(0)" ::: "memory")
#define BAR() do { asm volatile("" ::: "memory"); \
                   __builtin_amdgcn_s_barrier();  \
                   asm volatile("" ::: "memory"); } while (0)

__device__ __forceinline__ float wave_reduce_add(float v) {
#pragma unroll
    for (int off = 32; off > 0; off >>= 1) v += __shfl_xor(v, off, 64);
    return v;
}

// ---- Kernel A (fused): normalize -> fp8 K (x64 pre-scale, INTERLEAVED),
//      positives, zero rowsum, zero S-scratch, zero out.
__global__ __launch_bounds__(256)
void norm_pos_kernel(const float* __restrict__ zi, const float* __restrict__ zj,
                     unsigned int* __restrict__ Kf, float* __restrict__ rowsum,
                     float* __restrict__ pos, float* __restrict__ Sq,
                     float* __restrict__ out, int n_half) {
    const int i = blockIdx.x;
    const int t = threadIdx.x;                 // 256 threads x 4 floats = 1024
    float4 a = reinterpret_cast<const float4*>(zi + (size_t)i * D_DIM)[t];
    float4 b = reinterpret_cast<const float4*>(zj + (size_t)i * D_DIM)[t];
    float ssa = a.x*a.x + a.y*a.y + a.z*a.z + a.w*a.w;
    float ssb = b.x*b.x + b.y*b.y + b.z*b.z + b.w*b.w;
    float dab = a.x*b.x + a.y*b.y + a.z*b.z + a.w*b.w;
    ssa = wave_reduce_add(ssa);
    ssb = wave_reduce_add(ssb);
    dab = wave_reduce_add(dab);
    __shared__ float wsa[4], wsb[4], wsd[4];
    if ((t & 63) == 0) { wsa[t>>6] = ssa; wsb[t>>6] = ssb; wsd[t>>6] = dab; }
    __syncthreads();
    const float inva = 1.0f / sqrtf(wsa[0] + wsa[1] + wsa[2] + wsa[3]);
    const float invb = 1.0f / sqrtf(wsb[0] + wsb[1] + wsb[2] + wsb[3]);
    const float sa = inva * 64.0f;             // x64: keeps e4m3 in normal range
    const float sb = invb * 64.0f;
    unsigned int ua = 0, ub = 0;
    ua = __builtin_amdgcn_cvt_pk_fp8_f32(a.x * sa, a.y * sa, ua, false);
    ua = __builtin_amdgcn_cvt_pk_fp8_f32(a.z * sa, a.w * sa, ua, true);
    ub = __builtin_amdgcn_cvt_pk_fp8_f32(b.x * sb, b.y * sb, ub, false);
    ub = __builtin_amdgcn_cvt_pk_fp8_f32(b.z * sb, b.w * sb, ub, true);
    const int w = (t >> 4) * 16 + ((t >> 1) & 3) * 4 + ((t >> 3) & 1) * 2 + (t & 1);
    Kf[(size_t)i * 256 + w] = ua;                          // 1024 B row = 256 u32
    Kf[(size_t)(i + n_half) * 256 + w] = ub;
    Sq[(size_t)i * 256 + t] = 0.0f;            // 4096*256 = 32 tiles * 32768 floats
    if (t == 0) {
        pos[i] = (wsd[0] + wsd[1] + wsd[2] + wsd[3]) * inva * invb;
        rowsum[i] = 0.0f;
        rowsum[i + n_half] = 0.0f;
        if (i == 0) out[0] = 0.0f;             // loss kernel atomically accumulates
    }
}

// ---- Kernel B: triangular 256x128 tiles, fp8 plain MFMA (R14 config) --------
// + tail-quantization fix: tiles (by=0, bx<32) are pulled out of the normal
// set (leaving EXACTLY 1024 uniform jobs = 2 generations on 512 slots) and
// re-dispatched as 128 K-QUARTER blocks (4 K-tiles each) with the HIGHEST
// blockIdx, so they fill the third generation with ~1/4-length jobs:
// makespan ~2.25u instead of 3u. Quarter blocks run the identical pipeline
// (nt=4, K-offset q*4) and atomicAdd raw partial sums into S-scratch
// (zeroed in kernel A); fixup_kernel completes sum->exp->reduce.
// Normal path = R14 verbatim via its own run(0,16) expansion.
__global__ __launch_bounds__(512, 4)
void simclr_gemm_kernel(const unsigned char* __restrict__ Kmat,
                        float* __restrict__ rowsum, float* __restrict__ Sq,
                        int n_total) {
    __shared__ char lds[73728];

    const int tid  = threadIdx.x;
    const int lane = tid & 63;
    const int wave = tid >> 6;          // 0..7
    const int wr = wave >> 1;           // 0..3  (A rows wr*64)
    const int wc = wave & 1;            // 0..1  (B cols wc*64)
    const int kgrp = lane >> 4;         // 16B fragment slot within 64B row

    int rowbase, colbase, k0, stile = 0;
    bool diag = false, quarter;
    if (blockIdx.x < 1024) {
        // bijective XCD swizzle over the 1024 normal jobs; wg in [32, 1056)
        const int wg = 32 + ((blockIdx.x & 7) * 128 + (blockIdx.x >> 3));
        int by = 0, start = 0;
        while (wg >= start + (64 - 2 * by)) { start += 64 - 2 * by; ++by; }
        const int bx = 2 * by + (wg - start);
        diag = ((bx >> 1) == by);
        rowbase = by * BM;
        colbase = bx * BN;
        k0 = 0;
        quarter = false;
    } else {
        const int r = blockIdx.x - 1024;       // 0..127, dispatched last
        stile = r >> 2;                        // split tile: by=0, bx=stile
        const int q = r & 3;                   // K quarter
        rowbase = 0;
        colbase = stile * BN;
        k0 = q * 4;
        quarter = true;
    }

    const char* gK = reinterpret_cast<const char*>(Kmat);
    const int srow = tid >> 2;                          // 0..127 per 8KB issue
    const int sswz = (tid & 3) ^ ((srow >> 1) & 3);     // inverse-swizzled slot

    // stage full K-tile a (absolute) into ring slot a%3: A 2 issues + B 1 issue
    auto stage_all = [&](int a) {
        const int s = a % 3;
        const size_t kbyte = (size_t)a * BK;            // 64 B per row chunk
        char* dstA = lds + s * SLOT + tid * 16;
        char* dstB = lds + s * SLOT + 16384 + tid * 16;
#pragma unroll
        for (int i = 0; i < 2; ++i) {
            const int row = i * 128 + srow;
            const char* src = gK + (size_t)(rowbase + row) * D_DIM + kbyte + sswz * 16;
            __builtin_amdgcn_global_load_lds(
                (const __attribute__((address_space(1))) void*)src,
                (__attribute__((address_space(3))) void*)(dstA + i * 8192),
                16, 0, 0);
        }
        {
            const char* src = gK + (size_t)(colbase + srow) * D_DIM + kbyte + sswz * 16;
            __builtin_amdgcn_global_load_lds(
                (const __attribute__((address_space(1))) void*)src,
                (__attribute__((address_space(3))) void*)dstB,
                16, 0, 0);
        }
    };

    f32x4 acc[4][4] = {};              // [mi][ni] 16x16 frags (AGPR path)
    l64x2 af[4], bf[4];                // 16B fragments: .x = k-half0, .y = k-half1

    auto read_frag = [&](const char* base, int row) -> l64x2 {
        return *reinterpret_cast<const l64x2*>(
            base + row * 64 + ((kgrp ^ ((row >> 1) & 3)) << 4));
    };

    // R14-proven 1-barrier pipeline, specialized per call site (knt constant)
    auto run = [&](int kk0, int knt) {
        stage_all(kk0); stage_all(kk0 + 1);
        VMCNT(3); BAR();
        for (int t = 0; t < knt; ++t) {
            const int a = kk0 + t;
            const int s = a % 3;
            const char* Ab = lds + s * SLOT;
            const char* Bb = Ab + 16384;
#pragma unroll
            for (int mi = 0; mi < 4; ++mi)
                af[mi] = read_frag(Ab, wr * 64 + mi * 16 + (lane & 15));
#pragma unroll
            for (int ni = 0; ni < 4; ++ni)
                bf[ni] = read_frag(Bb, wc * 64 + ni * 16 + (lane & 15));
            if (t + 2 < knt) stage_all(a + 2);          // early prefetch issue
            __builtin_amdgcn_s_setprio(1);
#pragma unroll
            for (int mi = 0; mi < 4; ++mi)
#pragma unroll
                for (int ni = 0; ni < 4; ++ni)
                    acc[mi][ni] = __builtin_amdgcn_mfma_f32_16x16x32_fp8_fp8(
                        af[mi].x, bf[ni].x, acc[mi][ni], 0, 0, 0);
            __builtin_amdgcn_s_setprio(0);
            if (t < knt - 1) {
                LGKM0();                                // drain own reads pre-BAR
                if (t < knt - 2) { VMCNT(3); } else { VMCNT(0); }
                BAR();                                  // publish tile a+1
            }
            __builtin_amdgcn_s_setprio(1);
#pragma unroll
            for (int mi = 0; mi < 4; ++mi)
#pragma unroll
                for (int ni = 0; ni < 4; ++ni)
                    acc[mi][ni] = __builtin_amdgcn_mfma_f32_16x16x32_fp8_fp8(
                        af[mi].y, bf[ni].y, acc[mi][ni], 0, 0, 0);
            __builtin_amdgcn_s_setprio(0);
        }
    };

    if (!quarter) {
        run(0, NT);
        // R14 epilogue. C-frag: col = lane&15, row = (lane>>4)*4 + reg.
        float colpart[4] = {0.0f, 0.0f, 0.0f, 0.0f};
#pragma unroll
        for (int mi = 0; mi < 4; ++mi) {
#pragma unroll
            for (int reg = 0; reg < 4; ++reg) {
                const int grow = rowbase + wr * 64 + mi * 16 + ((lane >> 4) << 2) + reg;
                float rowpart = 0.0f;
#pragma unroll
                for (int ni = 0; ni < 4; ++ni) {
                    const int gcol = colbase + wc * 64 + ni * 16 + (lane & 15);
                    float e = __expf(acc[mi][ni][reg] * EXP_SCALE);
                    if (diag && grow == gcol) e = 0.0f;
                    rowpart += e;
                    colpart[ni] += e;
                }
#pragma unroll
                for (int off = 1; off < 16; off <<= 1)
                    rowpart += __shfl_xor(rowpart, off, 64);
                if ((lane & 15) == 0) atomicAdd(&rowsum[grow], rowpart);
            }
        }
        if (!diag) {
#pragma unroll
            for (int ni = 0; ni < 4; ++ni) {
                float cp = colpart[ni];
                cp += __shfl_xor(cp, 16, 64);
                cp += __shfl_xor(cp, 32, 64);
                if (lane < 16)
                    atomicAdd(&rowsum[colbase + wc * 64 + ni * 16 + lane], cp);
            }
        }
    } else {
        run(k0, 4);
        // raw partial-sim accumulation into S scratch (summed across quarters)
        float* St = Sq + (size_t)stile * (BM * BN);
#pragma unroll
        for (int mi = 0; mi < 4; ++mi) {
#pragma unroll
            for (int reg = 0; reg < 4; ++reg) {
                const int row = wr * 64 + mi * 16 + ((lane >> 4) << 2) + reg;
#pragma unroll
                for (int ni = 0; ni < 4; ++ni) {
                    const int col = wc * 64 + ni * 16 + (lane & 15);
                    atomicAdd(&St[row * BN + col], acc[mi][ni][reg]);
                }
            }
        }
    }
}

// ---- Kernel B2: fixup for split tiles — sum(4 quarters) already in Sq;
//      exp + row-reduce + (non-diag) col-reduce into rowsum.
// Split tiles: by=0 (rows 0..255), cols stile*128..+128; diag iff stile<2.
__global__ __launch_bounds__(512)
void fixup_kernel(const float* __restrict__ Sq, float* __restrict__ rowsum) {
    const int s = blockIdx.x;                  // 0..31
    const int lane = threadIdx.x & 63;
    const int wave = threadIdx.x >> 6;         // 0..7, rows wave*32..+32
    const float* St = Sq + (size_t)s * (BM * BN);
    const bool dtile = (s < 2);
    float cp0 = 0.0f, cp1 = 0.0f;
    for (int i = 0; i < 32; ++i) {
        const int r = wave * 32 + i;
        float e0 = __expf(St[r * BN + lane] * EXP_SCALE);
        float e1 = __expf(St[r * BN + 64 + lane] * EXP_SCALE);
        if (dtile) {
            if (r == s * BN + lane) e0 = 0.0f;          // exact diagonal
            if (r == s * BN + 64 + lane) e1 = 0.0f;
        }
        float rp = e0 + e1;
#pragma unroll
        for (int off = 1; off < 64; off <<= 1) rp += __shfl_xor(rp, off, 64);
        if (lane == 0) atomicAdd(&rowsum[r], rp);       // rowbase = 0
        cp0 += e0; cp1 += e1;
    }
    if (!dtile) {
        atomicAdd(&rowsum[s * BN + lane], cp0);
        atomicAdd(&rowsum[s * BN + 64 + lane], cp1);
    }
}

// ---- Kernel C: loss = mean(log(denom) - pos/tau), 32 blocks + atomicAdd ----
__global__ __launch_bounds__(256)
void loss_kernel(const float* __restrict__ rowsum, const float* __restrict__ pos,
                 float* __restrict__ out, int n_total, int n_half) {
    const int t = threadIdx.x;
    const int r = blockIdx.x * 256 + t;                 // 32 x 256 = 8192
    const int pi = (r < n_half) ? r : (r - n_half);
    float v = logf(rowsum[r]) - TAU_INV * pos[pi];
    v = wave_reduce_add(v);
    __shared__ float ws4[4];
    if ((t & 63) == 0) ws4[t >> 6] = v;
    __syncthreads();
    if (t == 0)
        atomicAdd(out, (ws4[0] + ws4[1] + ws4[2] + ws4[3]) / (float)n_total);
}

extern "C" void kernel_launch(void* const* d_in, const int* in_sizes, int n_in,
                              void* d_out, int out_size, void* d_ws, size_t ws_size,
                              hipStream_t stream) {
    const float* zi = (const float*)d_in[0];
    const float* zj = (const float*)d_in[1];
    float* out = (float*)d_out;

    const int n_half  = in_sizes[0] / D_DIM;   // 4096
    const int n_total = 2 * n_half;            // 8192

    char* ws = (char*)d_ws;
    unsigned int* Kf = (unsigned int*)ws;                 // 8192 x 1024 fp8 = 8 MB
    size_t off = (size_t)n_total * D_DIM;
    float* Sq     = (float*)(ws + off); off += (size_t)NSPLIT * BM * BN * 4;  // 4 MB
    float* rowsum = (float*)(ws + off); off += (size_t)n_total * 4;
    float* pos    = (float*)(ws + off); off += (size_t)n_half * 4;

    norm_pos_kernel<<<n_half, 256, 0, stream>>>(zi, zj, Kf, rowsum, pos, Sq, out, n_half);

    // 1024 normal tiles (2 exact generations) + 128 K-quarter blocks (tail)
    simclr_gemm_kernel<<<1024 + 4 * NSPLIT, 512, 0, stream>>>(
        (const unsigned char*)Kf, rowsum, Sq, n_total);

    fixup_kernel<<<NSPLIT, 512, 0, stream>>>(Sq, rowsum);

    loss_kernel<<<n_total / 256, 256, 0, stream>>>(rowsum, pos, out, n_total, n_half);
}